// Round 3
// baseline (176.909 us; speedup 1.0000x reference)
//
#include <hip/hip_runtime.h>

// DP5 integrator, MI355X. fp32 in/out. Rank-128 recursion vs G'=-256·(W@U).
// R16: register-level pipelining on top of R15 (bit-identical arithmetic —
// only load placement changed):
//  - all 32 U-pack B-fragments preloaded ONCE into VGPRs, shared by both
//    projection passes (was: reloaded from L2 inside both kb loops)
//  - pass-1 force rows prefetched before pass-0 compute (issue-early)
//  - recursion: 4 ds_read_b128 batched ahead of the 8-MFMA chain
//  - epilogue: cbi-invariant A-fragments hoisted (1x not 4x), W-pack B
//    double-buffered across cbi, x/v/f tail loads prefetched per-cbi
// k_prep is R15-verbatim (fused prep1+prep2, no cross-block dependency).

typedef _Float16 v8h __attribute__((ext_vector_type(8)));
typedef float v4f __attribute__((ext_vector_type(4)));
typedef unsigned short u16;
typedef unsigned int u32;

#define MFMAH __builtin_amdgcn_mfma_f32_16x16x32_f16
#define INV2048 4.8828125e-4f
#define INV256  0.00390625f
#define SSTR 144   // stage tile row stride (halfs)

struct Tab {
  double a[7][7]; double b[7]; double A[7]; double XC[7][7]; double XF[7]; double cxc[7];
};
static constexpr Tab make_tab() {
  Tab t{};
  t.a[2][1]=1.0/5;
  t.a[3][1]=3.0/40;       t.a[3][2]=9.0/40;
  t.a[4][1]=44.0/45;      t.a[4][2]=-56.0/15;      t.a[4][3]=32.0/9;
  t.a[5][1]=19372.0/6561; t.a[5][2]=-25360.0/2187; t.a[5][3]=64448.0/6561; t.a[5][4]=-212.0/729;
  t.a[6][1]=9017.0/3168;  t.a[6][2]=-355.0/33;     t.a[6][3]=46732.0/5247; t.a[6][4]=49.0/176; t.a[6][5]=-5103.0/18656;
  t.b[1]=35.0/384; t.b[2]=0.0; t.b[3]=500.0/1113; t.b[4]=125.0/192; t.b[5]=-2187.0/6784; t.b[6]=11.0/84;
  for (int i=1;i<=6;++i){ double s=0; for(int j=1;j<i;++j) s+=t.a[i][j]; t.A[i]=s; }
  for (int i=1;i<=6;++i) for(int l=1;l<i;++l){ double s=0; for(int j=l+1;j<i;++j) s+=t.a[i][j]*t.a[j][l]; t.XC[i][l]=s; }
  for (int i=1;i<=6;++i){ double s=0; for(int j=1;j<i;++j) s+=t.a[i][j]*t.A[j]; t.XF[i]=s; }
  for (int j=1;j<=6;++j){ double s=0; for (int i=j+1;i<=6;++i) s+=t.b[i]*t.a[i][j]; t.cxc[j]=s; }
  return t;
}
static constexpr Tab TB = make_tab();

__device__ __forceinline__ int decode_steps(const void* p){
  int v = *(const int*)p;
  if (v >= 1 && v <= 512) return v;
  float f = *(const float*)p;
  if (f >= 1.f && f <= 512.f) return (int)f;
  return 8;
}
__device__ __forceinline__ void split2s(float x, _Float16& h, _Float16& l){
  h = (_Float16)x;
  l = (_Float16)((x - (float)h) * 2048.0f);
}

#define WS_GH 0
#define WS_GL 16384
#define WS_UH 32768
#define WS_UL 98304
#define WS_WH 163840
#define WS_WL 229376

// ---- fused prep: blocks 0-7 = G' GEMM from raw U/W; blocks 8-263 = repack ----
__global__ __launch_bounds__(512) void k_prep(const float* __restrict__ Ug,
                                              const float* __restrict__ Wg,
                                              _Float16* __restrict__ ws){
  const int tid = threadIdx.x;
  if (blockIdx.x >= 8) {
    int t = (blockIdx.x - 8)*512 + tid;
    if (t < 65536) {
      int r = t >> 7, c = t & 127;
      _Float16 h, l; split2s(Ug[t]*256.f, h, l);
      int kb=r>>5, q2=(r>>3)&3, j=r&7, n2=c>>4, cl=c&15;
      int slot = ((n2*16+kb)*64 + q2*16+cl)*8 + j;
      ws[WS_UH + slot] = h; ws[WS_UL + slot] = l;
    } else {
      int idx = t - 65536;
      int r = idx >> 9, c = idx & 511;
      _Float16 h, l; split2s(Wg[idx]*256.f, h, l);
      int kb=r>>5, q2=(r>>3)&3, j=r&7, n2=c>>4, cl=c&15;
      int slot = ((n2*4+kb)*64 + q2*16+cl)*8 + j;
      ws[WS_WH + slot] = h; ws[WS_WL + slot] = l;
    }
  } else {
    const int b = blockIdx.x;
    const int ww = tid >> 6, lane = tid & 63, q = lane >> 4, c16 = lane & 15;
    const int nb = ww;
    v4f aH = {0,0,0,0}, aC0 = {0,0,0,0}, aC1 = {0,0,0,0};
    #pragma unroll
    for (int kb = 0; kb < 16; ++kb) {
      const float* wp = Wg + (b*16 + c16)*512 + kb*32 + q*8;
      float4 w0 = *(const float4*)wp;
      float4 w1 = *(const float4*)(wp + 4);
      float wv[8] = {w0.x,w0.y,w0.z,w0.w, w1.x,w1.y,w1.z,w1.w};
      v8h Ah, Al, Bh, Bl;
      #pragma unroll
      for (int j = 0; j < 8; ++j) {
        _Float16 h, l; split2s(-wv[j], h, l);
        Ah[j] = h; Al[j] = l;
        float uv = Ug[(kb*32 + q*8 + j)*128 + nb*16 + c16] * 256.f;
        split2s(uv, h, l);
        Bh[j] = h; Bl[j] = l;
      }
      aH = MFMAH(Ah, Bh, aH, 0,0,0);
      if (kb & 1) {
        aC1 = MFMAH(Ah, Bl, aC1, 0,0,0);
        aC1 = MFMAH(Al, Bh, aC1, 0,0,0);
      } else {
        aC0 = MFMAH(Ah, Bl, aC0, 0,0,0);
        aC0 = MFMAH(Al, Bh, aC0, 0,0,0);
      }
    }
    #pragma unroll
    for (int r = 0; r < 4; ++r) {
      float g = aH[r] + (aC0[r] + aC1[r])*INV2048;
      _Float16 h, l; split2s(g, h, l);
      int m = b*16 + 4*q + r, n = nb*16 + c16;
      int slot = (((n>>4)*4 + (m>>5))*64 + ((m>>3)&3)*16 + (n&15))*8 + (m&7);
      ws[WS_GH + slot] = h; ws[WS_GL + slot] = l;
    }
  }
}

#define ARENA 33280

__global__ __launch_bounds__(512,4) void dp5_main(
    const float* __restrict__ xg, const float* __restrict__ vg,
    const float* __restrict__ fg, const void* stepsp,
    const _Float16* __restrict__ ws, float* __restrict__ outg)
{
  __shared__ __align__(16) char arena[ARENA];
  _Float16* base = (_Float16*)arena;
  const _Float16* uH = ws + WS_UH;
  const _Float16* uL = ws + WS_UL;
  const _Float16* wH = ws + WS_WH;
  const _Float16* wL = ws + WS_WL;

  const int tid  = threadIdx.x;
  const int ww   = tid >> 6;
  const int lane = tid & 63;
  const int q    = lane >> 4;
  const int c16  = lane & 15;
  const int nb   = ww;
  const int kcol = nb*16 + c16;
  const int srcl = (q>>1)*16 + c16;
  const bool odd = (q & 1);
  const int rb   = blockIdx.x * 8;
  const int S    = decode_steps(stepsp);
  const float dt = 0.01f;
  // row-partner ownership
  const int  brow = c16 & 7;
  const bool hiC  = (c16 >= 8);
  const int  kc0  = nb*16 + 4*q + (hiC ? 2 : 0);   // owns cols kc0, kc0+1

  v8h Gh[4], Gl[4];
  #pragma unroll
  for (int kb = 0; kb < 4; ++kb) {
    int off = ((nb*4 + kb)*64 + lane)*8;
    Gh[kb] = *(const v8h*)(ws + WS_GH + off);
    Gl[kb] = *(const v8h*)(ws + WS_GL + off);
  }

  // R16: preload ALL U-pack B operands once (shared by both projection passes)
  v8h Bh_r[16], Bl_r[16];
  #pragma unroll
  for (int kb = 0; kb < 16; ++kb) {
    int bo = ((nb*16 + kb)*64 + lane)*8;
    Bh_r[kb] = *(const v8h*)(uH + bo);
    Bl_r[kb] = *(const v8h*)(uL + bo);
  }

  // ---- projections -> spread xU0/vU0/fU0 ----
  _Float16* tH = base;
  _Float16* tL = base + 8320;
  const int r16 = tid >> 5, c0 = (tid & 31)*16;

  // R16: prefetch pass-1 (force) rows early — consumed after pass-0 compute
  float4 fp0, fp1, fp2, fp3;
  if (r16 < 8) {
    const float* sp = fg + (rb + r16)*512 + c0;
    fp0 = *(const float4*)(sp);
    fp1 = *(const float4*)(sp + 4);
    fp2 = *(const float4*)(sp + 8);
    fp3 = *(const float4*)(sp + 12);
  }

  float xU0[2], vU0[2], fU0[2];
  for (int pass = 0; pass < 2; ++pass) {
    if (pass == 0 || r16 < 8) {
      float4 g0, g1, g2, g3;
      if (pass == 0) {
        const float* sp = (r16 < 8) ? (xg + (rb + r16)*512) : (vg + (rb + r16 - 8)*512);
        sp += c0;
        g0 = *(const float4*)(sp);
        g1 = *(const float4*)(sp + 4);
        g2 = *(const float4*)(sp + 8);
        g3 = *(const float4*)(sp + 12);
      } else {
        g0 = fp0; g1 = fp1; g2 = fp2; g3 = fp3;
      }
      float vals[16] = {g0.x,g0.y,g0.z,g0.w, g1.x,g1.y,g1.z,g1.w,
                        g2.x,g2.y,g2.z,g2.w, g3.x,g3.y,g3.z,g3.w};
      v8h vh0, vh1, vl0, vl1;
      #pragma unroll
      for (int j = 0; j < 8; ++j) {
        _Float16 h, l;
        split2s(vals[j], h, l);     vh0[j] = h; vl0[j] = l;
        split2s(vals[8+j], h, l);   vh1[j] = h; vl1[j] = l;
      }
      int o = r16*520 + c0;
      *(v8h*)(tH + o) = vh0; *(v8h*)(tH + o + 8) = vh1;
      *(v8h*)(tL + o) = vl0; *(v8h*)(tL + o + 8) = vl1;
    }
    __syncthreads();
    v4f aH0={0,0,0,0}, aH1={0,0,0,0}, aC0={0,0,0,0}, aC1={0,0,0,0};
    #pragma unroll
    for (int kb = 0; kb < 16; ++kb) {
      int ao = c16*520 + kb*32 + q*8;
      v8h Ah = *(const v8h*)(tH + ao);
      v8h Al = *(const v8h*)(tL + ao);
      if (kb & 1) {
        aH1 = MFMAH(Ah, Bh_r[kb], aH1, 0,0,0);
        aC1 = MFMAH(Ah, Bl_r[kb], aC1, 0,0,0);
        aC1 = MFMAH(Al, Bh_r[kb], aC1, 0,0,0);
      } else {
        aH0 = MFMAH(Ah, Bh_r[kb], aH0, 0,0,0);
        aC0 = MFMAH(Ah, Bl_r[kb], aC0, 0,0,0);
        aC0 = MFMAH(Al, Bh_r[kb], aC0, 0,0,0);
      }
    }
    float at0 = ((aH0[0]+aH1[0]) + (aC0[0]+aC1[0])*INV2048)*INV256;
    float at1 = ((aH0[1]+aH1[1]) + (aC0[1]+aC1[1])*INV2048)*INV256;
    float at2 = ((aH0[2]+aH1[2]) + (aC0[2]+aC1[2])*INV2048)*INV256;
    float at3 = ((aH0[3]+aH1[3]) + (aC0[3]+aC1[3])*INV2048)*INV256;
    if (pass == 0) {
      float sx0=__shfl(at0,srcl,64), sx1=__shfl(at1,srcl,64);
      float sx2=__shfl(at2,srcl,64), sx3=__shfl(at3,srcl,64);
      xU0[0] = odd ? sx2 : sx0; xU0[1] = odd ? sx3 : sx1;
      int srclv = srcl + 32;
      float sv0=__shfl(at0,srclv,64), sv1=__shfl(at1,srclv,64);
      float sv2=__shfl(at2,srclv,64), sv3=__shfl(at3,srclv,64);
      vU0[0] = odd ? sv2 : sv0; vU0[1] = odd ? sv3 : sv1;
    } else {
      float sf0=__shfl(at0,srcl,64), sf1=__shfl(at1,srcl,64);
      float sf2=__shfl(at2,srcl,64), sf3=__shfl(at3,srcl,64);
      fU0[0] = odd ? sf2 : sf0; fU0[1] = odd ? sf3 : sf1;
    }
    __syncthreads();
  }

  // ---- bounce spread -> row-partner state (float2 per lane) ----
  float cxU2[2], cvU2[2], fU2[2];
  {
    float* T = (float*)arena;
    #pragma unroll
    for (int p2 = 0; p2 < 3; ++p2) {
      float i0 = (p2==0) ? xU0[0] : (p2==1) ? vU0[0] : fU0[0];
      float i1 = (p2==0) ? xU0[1] : (p2==1) ? vU0[1] : fU0[1];
      T[(2*q + 0)*132 + kcol] = i0;
      T[(2*q + 1)*132 + kcol] = i1;
      __syncthreads();
      float2 t2 = *(const float2*)(T + brow*132 + kc0);
      float* o = (p2==0) ? cxU2 : (p2==1) ? cvU2 : fU2;
      o[0] = t2.x; o[1] = t2.y;
      __syncthreads();
    }
  }

  // ---- rank-128 recursion: transposed GEMM, balanced phase1 ----
  float kU6[6][2], Rr2[2], QXa2[2];
  #pragma unroll
  for (int j = 0; j < 2; ++j) {
    Rr2[j] = 0.f; QXa2[j] = 0.f;
    #pragma unroll
    for (int l = 0; l < 6; ++l) kU6[l][j] = 0.f;
  }

  int pb = 0;
  for (int s = 0; s < S; ++s) {
    float accX[2], accV[2], Pbs[2], Pxcs[2];
    #pragma unroll
    for (int j = 0; j < 2; ++j) { accX[j]=0.f; accV[j]=0.f; Pbs[j]=0.f; Pxcs[j]=0.f; }

    #pragma unroll
    for (int i = 1; i <= 6; ++i) {
      _Float16* bT = base + (pb ? 2304 : 0);
      const float dtA   = dt*(float)TB.A[i];
      const float dt2XF = dt*dt*(float)TB.XF[i];
      const float bi    = (float)TB.b[i];
      const float ci    = (float)TB.cxc[i];
      // phase1: all lanes, 2 cols each (row brow, cols kc0..kc0+1)
      {
        union { _Float16 h[2]; u32 u; } ph, pl;
        #pragma unroll
        for (int j2 = 0; j2 < 2; ++j2) {
          float vv = cvU2[j2] + dtA*fU2[j2];
          float xx = cxU2[j2] + dtA*cvU2[j2] + dt2XF*fU2[j2];
          #pragma unroll
          for (int l = 1; l < i; ++l) {
            vv += (dt*(float)TB.a[i][l]) * kU6[l-1][j2];
            xx += (dt*dt*(float)TB.XC[i][l]) * kU6[l-1][j2];
          }
          float p = vv*xx;
          Pbs[j2] += bi*p; Pxcs[j2] += ci*p;
          _Float16 h, l2; split2s(p, h, l2);
          ph.h[j2] = h; pl.h[j2] = l2;
        }
        *(u32*)(bT + brow*SSTR + kc0)       = ph.u;   // Ph rows 0-7
        *(u32*)(bT + (8+brow)*SSTR + kc0)   = pl.u;   // Pl rows 8-15
      }
      __syncthreads();
      // R16: batch the 4 ds_read_b128 ahead of the 8-MFMA chain
      const _Float16* bp = bT + c16*SSTR + q*8;
      v8h B0 = *(const v8h*)(bp);
      v8h B1 = *(const v8h*)(bp + 32);
      v8h B2 = *(const v8h*)(bp + 64);
      v8h B3 = *(const v8h*)(bp + 96);
      v4f C1 = {0,0,0,0}, C2 = {0,0,0,0};
      C1 = MFMAH(Gh[0], B0, C1, 0,0,0);  C2 = MFMAH(Gl[0], B0, C2, 0,0,0);
      C1 = MFMAH(Gh[1], B1, C1, 0,0,0);  C2 = MFMAH(Gl[1], B1, C2, 0,0,0);
      C1 = MFMAH(Gh[2], B2, C1, 0,0,0);  C2 = MFMAH(Gl[2], B2, C2, 0,0,0);
      C1 = MFMAH(Gh[3], B3, C1, 0,0,0);  C2 = MFMAH(Gl[3], B3, C2, 0,0,0);
      // combine (valid on c16<8), distribute regs 2,3 to partners
      float kv[4];
      #pragma unroll
      for (int r = 0; r < 4; ++r) {
        float oth = __shfl_xor(C1[r], 8, 64);
        kv[r] = (C1[r] + (oth + C2[r])*INV2048)*INV256;
      }
      float k2 = __shfl_xor(kv[2], 8, 64);
      float k3 = __shfl_xor(kv[3], 8, 64);
      float kva = hiC ? k2 : kv[0];
      float kvb = hiC ? k3 : kv[1];
      kU6[i-1][0] = kva; kU6[i-1][1] = kvb;
      accX[0] += ci*kva; accV[0] += bi*kva;
      accX[1] += ci*kvb; accV[1] += bi*kvb;
      pb ^= 1;
    }

    #pragma unroll
    for (int j = 0; j < 2; ++j) {
      float nx = cxU2[j] + dt*cvU2[j] + dt*dt*(accX[j] + 0.5f*fU2[j]);
      cvU2[j] += dt*(accV[j] + fU2[j]);
      cxU2[j]  = nx;
      QXa2[j] += Rr2[j] + Pxcs[j];
      Rr2[j]  += Pbs[j];
    }
  }

  // ---- epilogue: fill R|QX tiles (rows 0-7 = R, 8-15 = QX; h/l) ----
  __syncthreads();
  _Float16* RQh = base;
  _Float16* RQl = base + 2176;
  {
    union { _Float16 h[2]; u32 u; } t1, t2, t3, t4;
    #pragma unroll
    for (int j2 = 0; j2 < 2; ++j2) {
      _Float16 h, l;
      split2s(Rr2[j2], h, l);  t1.h[j2] = h; t2.h[j2] = l;
      split2s(QXa2[j2], h, l); t3.h[j2] = h; t4.h[j2] = l;
    }
    *(u32*)(RQh + brow*136 + kc0)     = t1.u;
    *(u32*)(RQl + brow*136 + kc0)     = t2.u;
    *(u32*)(RQh + (8+brow)*136 + kc0) = t3.u;
    *(u32*)(RQl + (8+brow)*136 + kc0) = t4.u;
  }
  __syncthreads();

  // R16: hoist cbi-invariant A-fragments (RQ tiles) — load once, not 4x
  v8h EAh[4], EAl[4];
  #pragma unroll
  for (int kb = 0; kb < 4; ++kb) {
    int ao = c16*136 + kb*32 + q*8;
    EAh[kb] = *(const v8h*)(RQh + ao);
    EAl[kb] = *(const v8h*)(RQl + ao);
  }
  // R16: double-buffer W-pack B-fragments across cbi
  v8h WBh[2][4], WBl[2][4];
  #pragma unroll
  for (int kb = 0; kb < 4; ++kb) {
    int bo = (((nb*4 + 0)*4 + kb)*64 + lane)*8;
    WBh[0][kb] = *(const v8h*)(wH + bo);
    WBl[0][kb] = *(const v8h*)(wL + bo);
  }

  const float Sdt = (float)S * dt;
  #pragma unroll
  for (int cbi = 0; cbi < 4; ++cbi) {
    int cb = nb*4 + cbi;
    const int cur = cbi & 1, nxt = cur ^ 1;
    if (cbi < 3) {
      #pragma unroll
      for (int kb = 0; kb < 4; ++kb) {
        int bo = (((nb*4 + cbi + 1)*4 + kb)*64 + lane)*8;
        WBh[nxt][kb] = *(const v8h*)(wH + bo);
        WBl[nxt][kb] = *(const v8h*)(wL + bo);
      }
    }
    // R16: prefetch x/v/f tail loads above the MFMA chain
    float px[4], pv[4], pf[4];
    if (q < 2) {
      #pragma unroll
      for (int i4 = 0; i4 < 4; ++i4) {
        int off = (rb + 4*q + i4)*512 + cb*16 + c16;
        px[i4] = xg[off]; pv[i4] = vg[off]; pf[i4] = fg[off];
      }
    }
    v4f aH={0,0,0,0}, aC0={0,0,0,0}, aC1={0,0,0,0};
    #pragma unroll
    for (int kb = 0; kb < 4; ++kb) {
      aH = MFMAH(EAh[kb], WBh[cur][kb], aH, 0,0,0);
      if (kb & 1) {
        aC1 = MFMAH(EAh[kb], WBl[cur][kb], aC1, 0,0,0);
        aC1 = MFMAH(EAl[kb], WBh[cur][kb], aC1, 0,0,0);
      } else {
        aC0 = MFMAH(EAh[kb], WBl[cur][kb], aC0, 0,0,0);
        aC0 = MFMAH(EAl[kb], WBh[cur][kb], aC0, 0,0,0);
      }
    }
    float r0 = (aH[0] + (aC0[0]+aC1[0])*INV2048)*INV256;
    float r1 = (aH[1] + (aC0[1]+aC1[1])*INV2048)*INV256;
    float r2 = (aH[2] + (aC0[2]+aC1[2])*INV2048)*INV256;
    float r3 = (aH[3] + (aC0[3]+aC1[3])*INV2048)*INV256;
    float o0 = __shfl_xor(r0, 32, 64);
    float o1 = __shfl_xor(r1, 32, 64);
    float o2 = __shfl_xor(r2, 32, 64);
    float o3 = __shfl_xor(r3, 32, 64);
    if (q < 2) {
      float abv[4] = {r0, r1, r2, r3};
      float axv[4] = {o0, o1, o2, o3};
      #pragma unroll
      for (int i4 = 0; i4 < 4; ++i4) {
        int off = (rb + 4*q + i4)*512 + cb*16 + c16;
        outg[off]           = px[i4] + Sdt*pv[i4] + 0.5f*Sdt*Sdt*pf[i4] - dt*dt*axv[i4];
        outg[2097152 + off] = pv[i4] + Sdt*pf[i4] - dt*abv[i4];
      }
    }
  }
}

extern "C" void kernel_launch(void* const* d_in, const int* in_sizes, int n_in,
                              void* d_out, int out_size, void* d_ws, size_t ws_size,
                              hipStream_t stream) {
  const float* x = (const float*)d_in[0];
  const float* v = (const float*)d_in[1];
  const float* f = (const float*)d_in[2];
  const float* U = (const float*)d_in[3];
  const float* W = (const float*)d_in[4];
  _Float16* ws = (_Float16*)d_ws;

  k_prep<<<dim3(264), dim3(512), 0, stream>>>(U, W, ws);
  dp5_main<<<dim3(512), dim3(512), 0, stream>>>(
      x, v, f, d_in[5], ws, (float*)d_out);
}

// Round 4
// 145.746 us; speedup vs baseline: 1.2138x; 1.2138x over previous
//
#include <hip/hip_runtime.h>

// DP5 integrator, MI355X. fp32 in/out. Rank-128 recursion vs G'=-256·(W@U).
// R17: R15 structure (fused k_prep + verified dp5_main) with ONE change:
// the six per-stage __shfl_xor(x, 8) exchanges in the recursion combine are
// replaced by DPP row_ror:8 (v_mov_b32 dpp, VALU pipe) — bit-identical
// lane^8 exchange (stays within a 16-lane DPP row), zero DS-pipe traffic.
// Theory: recursion is DS-pipe throughput-bound (~192 DS ops/stage/CU, half
// of them ds_bpermute from shfl_xor); this halves DS ops per stage and
// removes two serial bpermute rounds (~120-200cyc each) from the critical
// path. R16's register hoists are fully reverted (they spilled to scratch:
// VGPR cap 128 at __launch_bounds__(512,4); FETCH/WRITE tripled).

typedef _Float16 v8h __attribute__((ext_vector_type(8)));
typedef float v4f __attribute__((ext_vector_type(4)));
typedef unsigned short u16;
typedef unsigned int u32;

#define MFMAH __builtin_amdgcn_mfma_f32_16x16x32_f16
#define INV2048 4.8828125e-4f
#define INV256  0.00390625f
#define SSTR 144   // stage tile row stride (halfs)

// lane^8 exchange on the VALU pipe: DPP row_ror:8 (rows are 16 lanes; ror by
// 8 within a 16-lane row == xor 8). dpp_ctrl = 0x120|8, full row/bank masks.
__device__ __forceinline__ float swap8(float x){
  return __int_as_float(
    __builtin_amdgcn_mov_dpp(__float_as_int(x), 0x128, 0xf, 0xf, true));
}

struct Tab {
  double a[7][7]; double b[7]; double A[7]; double XC[7][7]; double XF[7]; double cxc[7];
};
static constexpr Tab make_tab() {
  Tab t{};
  t.a[2][1]=1.0/5;
  t.a[3][1]=3.0/40;       t.a[3][2]=9.0/40;
  t.a[4][1]=44.0/45;      t.a[4][2]=-56.0/15;      t.a[4][3]=32.0/9;
  t.a[5][1]=19372.0/6561; t.a[5][2]=-25360.0/2187; t.a[5][3]=64448.0/6561; t.a[5][4]=-212.0/729;
  t.a[6][1]=9017.0/3168;  t.a[6][2]=-355.0/33;     t.a[6][3]=46732.0/5247; t.a[6][4]=49.0/176; t.a[6][5]=-5103.0/18656;
  t.b[1]=35.0/384; t.b[2]=0.0; t.b[3]=500.0/1113; t.b[4]=125.0/192; t.b[5]=-2187.0/6784; t.b[6]=11.0/84;
  for (int i=1;i<=6;++i){ double s=0; for(int j=1;j<i;++j) s+=t.a[i][j]; t.A[i]=s; }
  for (int i=1;i<=6;++i) for(int l=1;l<i;++l){ double s=0; for(int j=l+1;j<i;++j) s+=t.a[i][j]*t.a[j][l]; t.XC[i][l]=s; }
  for (int i=1;i<=6;++i){ double s=0; for(int j=1;j<i;++j) s+=t.a[i][j]*t.A[j]; t.XF[i]=s; }
  for (int j=1;j<=6;++j){ double s=0; for (int i=j+1;i<=6;++i) s+=t.b[i]*t.a[i][j]; t.cxc[j]=s; }
  return t;
}
static constexpr Tab TB = make_tab();

__device__ __forceinline__ int decode_steps(const void* p){
  int v = *(const int*)p;
  if (v >= 1 && v <= 512) return v;
  float f = *(const float*)p;
  if (f >= 1.f && f <= 512.f) return (int)f;
  return 8;
}
__device__ __forceinline__ void split2s(float x, _Float16& h, _Float16& l){
  h = (_Float16)x;
  l = (_Float16)((x - (float)h) * 2048.0f);
}

#define WS_GH 0
#define WS_GL 16384
#define WS_UH 32768
#define WS_UL 98304
#define WS_WH 163840
#define WS_WL 229376

// ---- fused prep: blocks 0-7 = G' GEMM from raw U/W; blocks 8-263 = repack ----
__global__ __launch_bounds__(512) void k_prep(const float* __restrict__ Ug,
                                              const float* __restrict__ Wg,
                                              _Float16* __restrict__ ws){
  const int tid = threadIdx.x;
  if (blockIdx.x >= 8) {
    int t = (blockIdx.x - 8)*512 + tid;
    if (t < 65536) {
      int r = t >> 7, c = t & 127;
      _Float16 h, l; split2s(Ug[t]*256.f, h, l);
      int kb=r>>5, q2=(r>>3)&3, j=r&7, n2=c>>4, cl=c&15;
      int slot = ((n2*16+kb)*64 + q2*16+cl)*8 + j;
      ws[WS_UH + slot] = h; ws[WS_UL + slot] = l;
    } else {
      int idx = t - 65536;
      int r = idx >> 9, c = idx & 511;
      _Float16 h, l; split2s(Wg[idx]*256.f, h, l);
      int kb=r>>5, q2=(r>>3)&3, j=r&7, n2=c>>4, cl=c&15;
      int slot = ((n2*4+kb)*64 + q2*16+cl)*8 + j;
      ws[WS_WH + slot] = h; ws[WS_WL + slot] = l;
    }
  } else {
    const int b = blockIdx.x;
    const int ww = tid >> 6, lane = tid & 63, q = lane >> 4, c16 = lane & 15;
    const int nb = ww;
    v4f aH = {0,0,0,0}, aC0 = {0,0,0,0}, aC1 = {0,0,0,0};
    #pragma unroll
    for (int kb = 0; kb < 16; ++kb) {
      const float* wp = Wg + (b*16 + c16)*512 + kb*32 + q*8;
      float4 w0 = *(const float4*)wp;
      float4 w1 = *(const float4*)(wp + 4);
      float wv[8] = {w0.x,w0.y,w0.z,w0.w, w1.x,w1.y,w1.z,w1.w};
      v8h Ah, Al, Bh, Bl;
      #pragma unroll
      for (int j = 0; j < 8; ++j) {
        _Float16 h, l; split2s(-wv[j], h, l);
        Ah[j] = h; Al[j] = l;
        float uv = Ug[(kb*32 + q*8 + j)*128 + nb*16 + c16] * 256.f;
        split2s(uv, h, l);
        Bh[j] = h; Bl[j] = l;
      }
      aH = MFMAH(Ah, Bh, aH, 0,0,0);
      if (kb & 1) {
        aC1 = MFMAH(Ah, Bl, aC1, 0,0,0);
        aC1 = MFMAH(Al, Bh, aC1, 0,0,0);
      } else {
        aC0 = MFMAH(Ah, Bl, aC0, 0,0,0);
        aC0 = MFMAH(Al, Bh, aC0, 0,0,0);
      }
    }
    #pragma unroll
    for (int r = 0; r < 4; ++r) {
      float g = aH[r] + (aC0[r] + aC1[r])*INV2048;
      _Float16 h, l; split2s(g, h, l);
      int m = b*16 + 4*q + r, n = nb*16 + c16;
      int slot = (((n>>4)*4 + (m>>5))*64 + ((m>>3)&3)*16 + (n&15))*8 + (m&7);
      ws[WS_GH + slot] = h; ws[WS_GL + slot] = l;
    }
  }
}

#define ARENA 33280

__global__ __launch_bounds__(512,4) void dp5_main(
    const float* __restrict__ xg, const float* __restrict__ vg,
    const float* __restrict__ fg, const void* stepsp,
    const _Float16* __restrict__ ws, float* __restrict__ outg)
{
  __shared__ __align__(16) char arena[ARENA];
  _Float16* base = (_Float16*)arena;
  const _Float16* uH = ws + WS_UH;
  const _Float16* uL = ws + WS_UL;
  const _Float16* wH = ws + WS_WH;
  const _Float16* wL = ws + WS_WL;

  const int tid  = threadIdx.x;
  const int ww   = tid >> 6;
  const int lane = tid & 63;
  const int q    = lane >> 4;
  const int c16  = lane & 15;
  const int nb   = ww;
  const int kcol = nb*16 + c16;
  const int srcl = (q>>1)*16 + c16;
  const bool odd = (q & 1);
  const int rb   = blockIdx.x * 8;
  const int S    = decode_steps(stepsp);
  const float dt = 0.01f;
  // row-partner ownership
  const int  brow = c16 & 7;
  const bool hiC  = (c16 >= 8);
  const int  kc0  = nb*16 + 4*q + (hiC ? 2 : 0);   // owns cols kc0, kc0+1

  v8h Gh[4], Gl[4];
  #pragma unroll
  for (int kb = 0; kb < 4; ++kb) {
    int off = ((nb*4 + kb)*64 + lane)*8;
    Gh[kb] = *(const v8h*)(ws + WS_GH + off);
    Gl[kb] = *(const v8h*)(ws + WS_GL + off);
  }

  // ---- projections (R11-verbatim) -> spread xU0/vU0/fU0 ----
  _Float16* tH = base;
  _Float16* tL = base + 8320;
  const int r16 = tid >> 5, c0 = (tid & 31)*16;
  float xU0[2], vU0[2], fU0[2];
  for (int pass = 0; pass < 2; ++pass) {
    if (pass == 0 || r16 < 8) {
      const float* sp;
      if (pass == 0) sp = (r16 < 8) ? (xg + (rb + r16)*512) : (vg + (rb + r16 - 8)*512);
      else           sp = fg + (rb + r16)*512;
      sp += c0;
      float4 g0 = *(const float4*)(sp);
      float4 g1 = *(const float4*)(sp + 4);
      float4 g2 = *(const float4*)(sp + 8);
      float4 g3 = *(const float4*)(sp + 12);
      float vals[16] = {g0.x,g0.y,g0.z,g0.w, g1.x,g1.y,g1.z,g1.w,
                        g2.x,g2.y,g2.z,g2.w, g3.x,g3.y,g3.z,g3.w};
      v8h vh0, vh1, vl0, vl1;
      #pragma unroll
      for (int j = 0; j < 8; ++j) {
        _Float16 h, l;
        split2s(vals[j], h, l);     vh0[j] = h; vl0[j] = l;
        split2s(vals[8+j], h, l);   vh1[j] = h; vl1[j] = l;
      }
      int o = r16*520 + c0;
      *(v8h*)(tH + o) = vh0; *(v8h*)(tH + o + 8) = vh1;
      *(v8h*)(tL + o) = vl0; *(v8h*)(tL + o + 8) = vl1;
    }
    __syncthreads();
    v4f aH0={0,0,0,0}, aH1={0,0,0,0}, aC0={0,0,0,0}, aC1={0,0,0,0};
    #pragma unroll
    for (int kb = 0; kb < 16; ++kb) {
      int ao = c16*520 + kb*32 + q*8;
      v8h Ah = *(const v8h*)(tH + ao);
      v8h Al = *(const v8h*)(tL + ao);
      int bo = ((nb*16 + kb)*64 + lane)*8;
      v8h Bh = *(const v8h*)(uH + bo);
      v8h Bl = *(const v8h*)(uL + bo);
      if (kb & 1) {
        aH1 = MFMAH(Ah, Bh, aH1, 0,0,0);
        aC1 = MFMAH(Ah, Bl, aC1, 0,0,0);
        aC1 = MFMAH(Al, Bh, aC1, 0,0,0);
      } else {
        aH0 = MFMAH(Ah, Bh, aH0, 0,0,0);
        aC0 = MFMAH(Ah, Bl, aC0, 0,0,0);
        aC0 = MFMAH(Al, Bh, aC0, 0,0,0);
      }
    }
    float at0 = ((aH0[0]+aH1[0]) + (aC0[0]+aC1[0])*INV2048)*INV256;
    float at1 = ((aH0[1]+aH1[1]) + (aC0[1]+aC1[1])*INV2048)*INV256;
    float at2 = ((aH0[2]+aH1[2]) + (aC0[2]+aC1[2])*INV2048)*INV256;
    float at3 = ((aH0[3]+aH1[3]) + (aC0[3]+aC1[3])*INV2048)*INV256;
    if (pass == 0) {
      float sx0=__shfl(at0,srcl,64), sx1=__shfl(at1,srcl,64);
      float sx2=__shfl(at2,srcl,64), sx3=__shfl(at3,srcl,64);
      xU0[0] = odd ? sx2 : sx0; xU0[1] = odd ? sx3 : sx1;
      int srclv = srcl + 32;
      float sv0=__shfl(at0,srclv,64), sv1=__shfl(at1,srclv,64);
      float sv2=__shfl(at2,srclv,64), sv3=__shfl(at3,srclv,64);
      vU0[0] = odd ? sv2 : sv0; vU0[1] = odd ? sv3 : sv1;
    } else {
      float sf0=__shfl(at0,srcl,64), sf1=__shfl(at1,srcl,64);
      float sf2=__shfl(at2,srcl,64), sf3=__shfl(at3,srcl,64);
      fU0[0] = odd ? sf2 : sf0; fU0[1] = odd ? sf3 : sf1;
    }
    __syncthreads();
  }

  // ---- bounce spread -> row-partner state (float2 per lane) ----
  float cxU2[2], cvU2[2], fU2[2];
  {
    float* T = (float*)arena;
    #pragma unroll
    for (int p2 = 0; p2 < 3; ++p2) {
      float i0 = (p2==0) ? xU0[0] : (p2==1) ? vU0[0] : fU0[0];
      float i1 = (p2==0) ? xU0[1] : (p2==1) ? vU0[1] : fU0[1];
      T[(2*q + 0)*132 + kcol] = i0;
      T[(2*q + 1)*132 + kcol] = i1;
      __syncthreads();
      float2 t2 = *(const float2*)(T + brow*132 + kc0);
      float* o = (p2==0) ? cxU2 : (p2==1) ? cvU2 : fU2;
      o[0] = t2.x; o[1] = t2.y;
      __syncthreads();
    }
  }

  // ---- rank-128 recursion: transposed GEMM, balanced phase1 ----
  float kU6[6][2], Rr2[2], QXa2[2];
  #pragma unroll
  for (int j = 0; j < 2; ++j) {
    Rr2[j] = 0.f; QXa2[j] = 0.f;
    #pragma unroll
    for (int l = 0; l < 6; ++l) kU6[l][j] = 0.f;
  }

  int pb = 0;
  for (int s = 0; s < S; ++s) {
    float accX[2], accV[2], Pbs[2], Pxcs[2];
    #pragma unroll
    for (int j = 0; j < 2; ++j) { accX[j]=0.f; accV[j]=0.f; Pbs[j]=0.f; Pxcs[j]=0.f; }

    #pragma unroll
    for (int i = 1; i <= 6; ++i) {
      _Float16* bT = base + (pb ? 2304 : 0);
      const float dtA   = dt*(float)TB.A[i];
      const float dt2XF = dt*dt*(float)TB.XF[i];
      const float bi    = (float)TB.b[i];
      const float ci    = (float)TB.cxc[i];
      // phase1: all lanes, 2 cols each (row brow, cols kc0..kc0+1)
      {
        union { _Float16 h[2]; u32 u; } ph, pl;
        #pragma unroll
        for (int j2 = 0; j2 < 2; ++j2) {
          float vv = cvU2[j2] + dtA*fU2[j2];
          float xx = cxU2[j2] + dtA*cvU2[j2] + dt2XF*fU2[j2];
          #pragma unroll
          for (int l = 1; l < i; ++l) {
            vv += (dt*(float)TB.a[i][l]) * kU6[l-1][j2];
            xx += (dt*dt*(float)TB.XC[i][l]) * kU6[l-1][j2];
          }
          float p = vv*xx;
          Pbs[j2] += bi*p; Pxcs[j2] += ci*p;
          _Float16 h, l2; split2s(p, h, l2);
          ph.h[j2] = h; pl.h[j2] = l2;
        }
        *(u32*)(bT + brow*SSTR + kc0)       = ph.u;   // Ph rows 0-7
        *(u32*)(bT + (8+brow)*SSTR + kc0)   = pl.u;   // Pl rows 8-15
      }
      __syncthreads();
      // transposed MFMA: A = G frags, B = packed P-tile
      v4f C1 = {0,0,0,0}, C2 = {0,0,0,0};
      #pragma unroll
      for (int kb = 0; kb < 4; ++kb) {
        v8h B = *(const v8h*)(bT + c16*SSTR + kb*32 + q*8);
        C1 = MFMAH(Gh[kb], B, C1, 0,0,0);
        C2 = MFMAH(Gl[kb], B, C2, 0,0,0);
      }
      // combine (valid on c16<8), distribute regs 2,3 to partners
      // R17: lane^8 exchange via DPP row_ror:8 (VALU), not ds_bpermute
      float kv[4];
      #pragma unroll
      for (int r = 0; r < 4; ++r) {
        float oth = swap8(C1[r]);
        kv[r] = (C1[r] + (oth + C2[r])*INV2048)*INV256;
      }
      float k2 = swap8(kv[2]);
      float k3 = swap8(kv[3]);
      float kva = hiC ? k2 : kv[0];
      float kvb = hiC ? k3 : kv[1];
      kU6[i-1][0] = kva; kU6[i-1][1] = kvb;
      accX[0] += ci*kva; accV[0] += bi*kva;
      accX[1] += ci*kvb; accV[1] += bi*kvb;
      pb ^= 1;
    }

    #pragma unroll
    for (int j = 0; j < 2; ++j) {
      float nx = cxU2[j] + dt*cvU2[j] + dt*dt*(accX[j] + 0.5f*fU2[j]);
      cvU2[j] += dt*(accV[j] + fU2[j]);
      cxU2[j]  = nx;
      QXa2[j] += Rr2[j] + Pxcs[j];
      Rr2[j]  += Pbs[j];
    }
  }

  // ---- epilogue: fill R|QX tiles (rows 0-7 = R, 8-15 = QX; h/l), R11 MFMA loop
  __syncthreads();
  _Float16* RQh = base;
  _Float16* RQl = base + 2176;
  {
    union { _Float16 h[2]; u32 u; } t1, t2, t3, t4;
    #pragma unroll
    for (int j2 = 0; j2 < 2; ++j2) {
      _Float16 h, l;
      split2s(Rr2[j2], h, l);  t1.h[j2] = h; t2.h[j2] = l;
      split2s(QXa2[j2], h, l); t3.h[j2] = h; t4.h[j2] = l;
    }
    *(u32*)(RQh + brow*136 + kc0)     = t1.u;
    *(u32*)(RQl + brow*136 + kc0)     = t2.u;
    *(u32*)(RQh + (8+brow)*136 + kc0) = t3.u;
    *(u32*)(RQl + (8+brow)*136 + kc0) = t4.u;
  }
  __syncthreads();

  const float Sdt = (float)S * dt;
  #pragma unroll
  for (int cbi = 0; cbi < 4; ++cbi) {
    int cb = nb*4 + cbi;
    v4f aH={0,0,0,0}, aC0={0,0,0,0}, aC1={0,0,0,0};
    #pragma unroll
    for (int kb = 0; kb < 4; ++kb) {
      int bo = ((cb*4 + kb)*64 + lane)*8;
      v8h Bh = *(const v8h*)(wH + bo);
      v8h Bl = *(const v8h*)(wL + bo);
      int ao = c16*136 + kb*32 + q*8;
      v8h Ah = *(const v8h*)(RQh + ao);
      v8h Al = *(const v8h*)(RQl + ao);
      aH = MFMAH(Ah, Bh, aH, 0,0,0);
      if (kb & 1) {
        aC1 = MFMAH(Ah, Bl, aC1, 0,0,0);
        aC1 = MFMAH(Al, Bh, aC1, 0,0,0);
      } else {
        aC0 = MFMAH(Ah, Bl, aC0, 0,0,0);
        aC0 = MFMAH(Al, Bh, aC0, 0,0,0);
      }
    }
    float r0 = (aH[0] + (aC0[0]+aC1[0])*INV2048)*INV256;
    float r1 = (aH[1] + (aC0[1]+aC1[1])*INV2048)*INV256;
    float r2 = (aH[2] + (aC0[2]+aC1[2])*INV2048)*INV256;
    float r3 = (aH[3] + (aC0[3]+aC1[3])*INV2048)*INV256;
    float o0 = __shfl_xor(r0, 32, 64);
    float o1 = __shfl_xor(r1, 32, 64);
    float o2 = __shfl_xor(r2, 32, 64);
    float o3 = __shfl_xor(r3, 32, 64);
    if (q < 2) {
      float abv[4] = {r0, r1, r2, r3};
      float axv[4] = {o0, o1, o2, o3};
      #pragma unroll
      for (int i4 = 0; i4 < 4; ++i4) {
        int off = (rb + 4*q + i4)*512 + cb*16 + c16;
        float x0 = xg[off], v0 = vg[off], f0 = fg[off];
        outg[off]           = x0 + Sdt*v0 + 0.5f*Sdt*Sdt*f0 - dt*dt*axv[i4];
        outg[2097152 + off] = v0 + Sdt*f0 - dt*abv[i4];
      }
    }
  }
}

extern "C" void kernel_launch(void* const* d_in, const int* in_sizes, int n_in,
                              void* d_out, int out_size, void* d_ws, size_t ws_size,
                              hipStream_t stream) {
  const float* x = (const float*)d_in[0];
  const float* v = (const float*)d_in[1];
  const float* f = (const float*)d_in[2];
  const float* U = (const float*)d_in[3];
  const float* W = (const float*)d_in[4];
  _Float16* ws = (_Float16*)d_ws;

  k_prep<<<dim3(264), dim3(512), 0, stream>>>(U, W, ws);
  dp5_main<<<dim3(512), dim3(512), 0, stream>>>(
      x, v, f, d_in[5], ws, (float*)d_out);
}

// Round 5
// 136.369 us; speedup vs baseline: 1.2973x; 1.0688x over previous
//
#include <hip/hip_runtime.h>

// DP5 integrator, MI355X. fp32 in/out. Rank-128 recursion vs G'=-256·(W@U).
// R18 = R17 (fused k_prep, DPP swap8) +
//  (a) merged projection passes: ONE kb loop, 24-row A-tile (x,v rows 0-15,
//      f rows 16-23; pass-1 A rows 8-15 read v rows = R15's exact stale data
//      -> bit-identical operands), shared Bh/Bl loads (halved L2 traffic).
//  (b) recursion: 4 ds_read_b128 batched ahead of the 8-MFMA chain.
//  (c) epilogue: axv/abv scattered to LDS, then coalesced float4 drain for
//      x/v/f reads and BOTH output writes (kills ~19MB of partial-line RMW
//      write amplification seen as WRITE_SIZE 35MB vs 16MB ideal).
// All arithmetic bit-identical to the verified R15/R17 path.

typedef _Float16 v8h __attribute__((ext_vector_type(8)));
typedef float v4f __attribute__((ext_vector_type(4)));
typedef unsigned short u16;
typedef unsigned int u32;

#define MFMAH __builtin_amdgcn_mfma_f32_16x16x32_f16
#define INV2048 4.8828125e-4f
#define INV256  0.00390625f
#define SSTR 144   // stage tile row stride (halfs)

// lane^8 exchange on the VALU pipe: DPP row_ror:8 (16-lane rows; ror 8 == xor 8)
__device__ __forceinline__ float swap8(float x){
  return __int_as_float(
    __builtin_amdgcn_mov_dpp(__float_as_int(x), 0x128, 0xf, 0xf, true));
}

struct Tab {
  double a[7][7]; double b[7]; double A[7]; double XC[7][7]; double XF[7]; double cxc[7];
};
static constexpr Tab make_tab() {
  Tab t{};
  t.a[2][1]=1.0/5;
  t.a[3][1]=3.0/40;       t.a[3][2]=9.0/40;
  t.a[4][1]=44.0/45;      t.a[4][2]=-56.0/15;      t.a[4][3]=32.0/9;
  t.a[5][1]=19372.0/6561; t.a[5][2]=-25360.0/2187; t.a[5][3]=64448.0/6561; t.a[5][4]=-212.0/729;
  t.a[6][1]=9017.0/3168;  t.a[6][2]=-355.0/33;     t.a[6][3]=46732.0/5247; t.a[6][4]=49.0/176; t.a[6][5]=-5103.0/18656;
  t.b[1]=35.0/384; t.b[2]=0.0; t.b[3]=500.0/1113; t.b[4]=125.0/192; t.b[5]=-2187.0/6784; t.b[6]=11.0/84;
  for (int i=1;i<=6;++i){ double s=0; for(int j=1;j<i;++j) s+=t.a[i][j]; t.A[i]=s; }
  for (int i=1;i<=6;++i) for(int l=1;l<i;++l){ double s=0; for(int j=l+1;j<i;++j) s+=t.a[i][j]*t.a[j][l]; t.XC[i][l]=s; }
  for (int i=1;i<=6;++i){ double s=0; for(int j=1;j<i;++j) s+=t.a[i][j]*t.A[j]; t.XF[i]=s; }
  for (int j=1;j<=6;++j){ double s=0; for (int i=j+1;i<=6;++i) s+=t.b[i]*t.a[i][j]; t.cxc[j]=s; }
  return t;
}
static constexpr Tab TB = make_tab();

__device__ __forceinline__ int decode_steps(const void* p){
  int v = *(const int*)p;
  if (v >= 1 && v <= 512) return v;
  float f = *(const float*)p;
  if (f >= 1.f && f <= 512.f) return (int)f;
  return 8;
}
__device__ __forceinline__ void split2s(float x, _Float16& h, _Float16& l){
  h = (_Float16)x;
  l = (_Float16)((x - (float)h) * 2048.0f);
}

#define WS_GH 0
#define WS_GL 16384
#define WS_UH 32768
#define WS_UL 98304
#define WS_WH 163840
#define WS_WL 229376

// ---- fused prep: blocks 0-7 = G' GEMM from raw U/W; blocks 8-263 = repack ----
__global__ __launch_bounds__(512) void k_prep(const float* __restrict__ Ug,
                                              const float* __restrict__ Wg,
                                              _Float16* __restrict__ ws){
  const int tid = threadIdx.x;
  if (blockIdx.x >= 8) {
    int t = (blockIdx.x - 8)*512 + tid;
    if (t < 65536) {
      int r = t >> 7, c = t & 127;
      _Float16 h, l; split2s(Ug[t]*256.f, h, l);
      int kb=r>>5, q2=(r>>3)&3, j=r&7, n2=c>>4, cl=c&15;
      int slot = ((n2*16+kb)*64 + q2*16+cl)*8 + j;
      ws[WS_UH + slot] = h; ws[WS_UL + slot] = l;
    } else {
      int idx = t - 65536;
      int r = idx >> 9, c = idx & 511;
      _Float16 h, l; split2s(Wg[idx]*256.f, h, l);
      int kb=r>>5, q2=(r>>3)&3, j=r&7, n2=c>>4, cl=c&15;
      int slot = ((n2*4+kb)*64 + q2*16+cl)*8 + j;
      ws[WS_WH + slot] = h; ws[WS_WL + slot] = l;
    }
  } else {
    const int b = blockIdx.x;
    const int ww = tid >> 6, lane = tid & 63, q = lane >> 4, c16 = lane & 15;
    const int nb = ww;
    v4f aH = {0,0,0,0}, aC0 = {0,0,0,0}, aC1 = {0,0,0,0};
    #pragma unroll
    for (int kb = 0; kb < 16; ++kb) {
      const float* wp = Wg + (b*16 + c16)*512 + kb*32 + q*8;
      float4 w0 = *(const float4*)wp;
      float4 w1 = *(const float4*)(wp + 4);
      float wv[8] = {w0.x,w0.y,w0.z,w0.w, w1.x,w1.y,w1.z,w1.w};
      v8h Ah, Al, Bh, Bl;
      #pragma unroll
      for (int j = 0; j < 8; ++j) {
        _Float16 h, l; split2s(-wv[j], h, l);
        Ah[j] = h; Al[j] = l;
        float uv = Ug[(kb*32 + q*8 + j)*128 + nb*16 + c16] * 256.f;
        split2s(uv, h, l);
        Bh[j] = h; Bl[j] = l;
      }
      aH = MFMAH(Ah, Bh, aH, 0,0,0);
      if (kb & 1) {
        aC1 = MFMAH(Ah, Bl, aC1, 0,0,0);
        aC1 = MFMAH(Al, Bh, aC1, 0,0,0);
      } else {
        aC0 = MFMAH(Ah, Bl, aC0, 0,0,0);
        aC0 = MFMAH(Al, Bh, aC0, 0,0,0);
      }
    }
    #pragma unroll
    for (int r = 0; r < 4; ++r) {
      float g = aH[r] + (aC0[r] + aC1[r])*INV2048;
      _Float16 h, l; split2s(g, h, l);
      int m = b*16 + 4*q + r, n = nb*16 + c16;
      int slot = (((n>>4)*4 + (m>>5))*64 + ((m>>3)&3)*16 + (n&15))*8 + (m&7);
      ws[WS_GH + slot] = h; ws[WS_GL + slot] = l;
    }
  }
}

// arena: projections need 2 * 24*520 halfs = 49920 B. Epilogue staging:
// ax at byte 9216 (16KB), ab at 25600 (16KB) -> ends 41984 < 49920.
#define ARENA 49920

__global__ __launch_bounds__(512,4) void dp5_main(
    const float* __restrict__ xg, const float* __restrict__ vg,
    const float* __restrict__ fg, const void* stepsp,
    const _Float16* __restrict__ ws, float* __restrict__ outg)
{
  __shared__ __align__(16) char arena[ARENA];
  _Float16* base = (_Float16*)arena;
  const _Float16* uH = ws + WS_UH;
  const _Float16* uL = ws + WS_UL;
  const _Float16* wH = ws + WS_WH;
  const _Float16* wL = ws + WS_WL;

  const int tid  = threadIdx.x;
  const int ww   = tid >> 6;
  const int lane = tid & 63;
  const int q    = lane >> 4;
  const int c16  = lane & 15;
  const int nb   = ww;
  const int kcol = nb*16 + c16;
  const int srcl = (q>>1)*16 + c16;
  const bool odd = (q & 1);
  const int rb   = blockIdx.x * 8;
  const int S    = decode_steps(stepsp);
  const float dt = 0.01f;
  // row-partner ownership
  const int  brow = c16 & 7;
  const bool hiC  = (c16 >= 8);
  const int  kc0  = nb*16 + 4*q + (hiC ? 2 : 0);   // owns cols kc0, kc0+1

  v8h Gh[4], Gl[4];
  #pragma unroll
  for (int kb = 0; kb < 4; ++kb) {
    int off = ((nb*4 + kb)*64 + lane)*8;
    Gh[kb] = *(const v8h*)(ws + WS_GH + off);
    Gl[kb] = *(const v8h*)(ws + WS_GL + off);
  }

  // ---- merged projections -> xU0/vU0/fU0 in one kb loop ----
  // 24-row tile: rows 0-7 = x, 8-15 = v, 16-23 = f. Pass-1 A rows 8-15 read
  // the v rows (== R15 pass-1 stale data), so operands are bit-identical.
  _Float16* tH = base;
  _Float16* tL = base + 12480;
  const int r16 = tid >> 5, c0 = (tid & 31)*16;
  float xU0[2], vU0[2], fU0[2];
  {
    // stage x/v rows (rows 0-15)
    {
      const float* sp = (r16 < 8) ? (xg + (rb + r16)*512) : (vg + (rb + r16 - 8)*512);
      sp += c0;
      float4 g0 = *(const float4*)(sp);
      float4 g1 = *(const float4*)(sp + 4);
      float4 g2 = *(const float4*)(sp + 8);
      float4 g3 = *(const float4*)(sp + 12);
      float vals[16] = {g0.x,g0.y,g0.z,g0.w, g1.x,g1.y,g1.z,g1.w,
                        g2.x,g2.y,g2.z,g2.w, g3.x,g3.y,g3.z,g3.w};
      v8h vh0, vh1, vl0, vl1;
      #pragma unroll
      for (int j = 0; j < 8; ++j) {
        _Float16 h, l;
        split2s(vals[j], h, l);     vh0[j] = h; vl0[j] = l;
        split2s(vals[8+j], h, l);   vh1[j] = h; vl1[j] = l;
      }
      int o = r16*520 + c0;
      *(v8h*)(tH + o) = vh0; *(v8h*)(tH + o + 8) = vh1;
      *(v8h*)(tL + o) = vl0; *(v8h*)(tL + o + 8) = vl1;
    }
    // stage f rows (rows 16-23)
    if (r16 < 8) {
      const float* sp = fg + (rb + r16)*512 + c0;
      float4 g0 = *(const float4*)(sp);
      float4 g1 = *(const float4*)(sp + 4);
      float4 g2 = *(const float4*)(sp + 8);
      float4 g3 = *(const float4*)(sp + 12);
      float vals[16] = {g0.x,g0.y,g0.z,g0.w, g1.x,g1.y,g1.z,g1.w,
                        g2.x,g2.y,g2.z,g2.w, g3.x,g3.y,g3.z,g3.w};
      v8h vh0, vh1, vl0, vl1;
      #pragma unroll
      for (int j = 0; j < 8; ++j) {
        _Float16 h, l;
        split2s(vals[j], h, l);     vh0[j] = h; vl0[j] = l;
        split2s(vals[8+j], h, l);   vh1[j] = h; vl1[j] = l;
      }
      int o = (16 + r16)*520 + c0;
      *(v8h*)(tH + o) = vh0; *(v8h*)(tH + o + 8) = vh1;
      *(v8h*)(tL + o) = vl0; *(v8h*)(tL + o + 8) = vl1;
    }
    __syncthreads();

    v4f aH0={0,0,0,0}, aH1={0,0,0,0}, aC0={0,0,0,0}, aC1={0,0,0,0};
    v4f bH0={0,0,0,0}, bH1={0,0,0,0}, bC0={0,0,0,0}, bC1={0,0,0,0};
    const int arow1 = (c16 < 8) ? (16 + c16) : c16;
    #pragma unroll
    for (int kb = 0; kb < 16; ++kb) {
      int ao0 = c16*520 + kb*32 + q*8;
      int ao1 = arow1*520 + kb*32 + q*8;
      v8h Ah0 = *(const v8h*)(tH + ao0);
      v8h Al0 = *(const v8h*)(tL + ao0);
      v8h Ah1 = *(const v8h*)(tH + ao1);
      v8h Al1 = *(const v8h*)(tL + ao1);
      int bo = ((nb*16 + kb)*64 + lane)*8;
      v8h Bh = *(const v8h*)(uH + bo);
      v8h Bl = *(const v8h*)(uL + bo);
      if (kb & 1) {
        aH1 = MFMAH(Ah0, Bh, aH1, 0,0,0);
        aC1 = MFMAH(Ah0, Bl, aC1, 0,0,0);
        aC1 = MFMAH(Al0, Bh, aC1, 0,0,0);
        bH1 = MFMAH(Ah1, Bh, bH1, 0,0,0);
        bC1 = MFMAH(Ah1, Bl, bC1, 0,0,0);
        bC1 = MFMAH(Al1, Bh, bC1, 0,0,0);
      } else {
        aH0 = MFMAH(Ah0, Bh, aH0, 0,0,0);
        aC0 = MFMAH(Ah0, Bl, aC0, 0,0,0);
        aC0 = MFMAH(Al0, Bh, aC0, 0,0,0);
        bH0 = MFMAH(Ah1, Bh, bH0, 0,0,0);
        bC0 = MFMAH(Ah1, Bl, bC0, 0,0,0);
        bC0 = MFMAH(Al1, Bh, bC0, 0,0,0);
      }
    }
    float at0 = ((aH0[0]+aH1[0]) + (aC0[0]+aC1[0])*INV2048)*INV256;
    float at1 = ((aH0[1]+aH1[1]) + (aC0[1]+aC1[1])*INV2048)*INV256;
    float at2 = ((aH0[2]+aH1[2]) + (aC0[2]+aC1[2])*INV2048)*INV256;
    float at3 = ((aH0[3]+aH1[3]) + (aC0[3]+aC1[3])*INV2048)*INV256;
    float bt0 = ((bH0[0]+bH1[0]) + (bC0[0]+bC1[0])*INV2048)*INV256;
    float bt1 = ((bH0[1]+bH1[1]) + (bC0[1]+bC1[1])*INV2048)*INV256;
    float bt2 = ((bH0[2]+bH1[2]) + (bC0[2]+bC1[2])*INV2048)*INV256;
    float bt3 = ((bH0[3]+bH1[3]) + (bC0[3]+bC1[3])*INV2048)*INV256;
    // pass-0 extraction (x from lanes 0-31, v from lanes 32-63)
    {
      float sx0=__shfl(at0,srcl,64), sx1=__shfl(at1,srcl,64);
      float sx2=__shfl(at2,srcl,64), sx3=__shfl(at3,srcl,64);
      xU0[0] = odd ? sx2 : sx0; xU0[1] = odd ? sx3 : sx1;
      int srclv = srcl + 32;
      float sv0=__shfl(at0,srclv,64), sv1=__shfl(at1,srclv,64);
      float sv2=__shfl(at2,srclv,64), sv3=__shfl(at3,srclv,64);
      vU0[0] = odd ? sv2 : sv0; vU0[1] = odd ? sv3 : sv1;
    }
    // pass-1 extraction (f from lanes 0-31)
    {
      float sf0=__shfl(bt0,srcl,64), sf1=__shfl(bt1,srcl,64);
      float sf2=__shfl(bt2,srcl,64), sf3=__shfl(bt3,srcl,64);
      fU0[0] = odd ? sf2 : sf0; fU0[1] = odd ? sf3 : sf1;
    }
    __syncthreads();
  }

  // ---- bounce spread -> row-partner state (float2 per lane) ----
  float cxU2[2], cvU2[2], fU2[2];
  {
    float* T = (float*)arena;
    #pragma unroll
    for (int p2 = 0; p2 < 3; ++p2) {
      float i0 = (p2==0) ? xU0[0] : (p2==1) ? vU0[0] : fU0[0];
      float i1 = (p2==0) ? xU0[1] : (p2==1) ? vU0[1] : fU0[1];
      T[(2*q + 0)*132 + kcol] = i0;
      T[(2*q + 1)*132 + kcol] = i1;
      __syncthreads();
      float2 t2 = *(const float2*)(T + brow*132 + kc0);
      float* o = (p2==0) ? cxU2 : (p2==1) ? cvU2 : fU2;
      o[0] = t2.x; o[1] = t2.y;
      __syncthreads();
    }
  }

  // ---- rank-128 recursion: transposed GEMM, balanced phase1 ----
  float kU6[6][2], Rr2[2], QXa2[2];
  #pragma unroll
  for (int j = 0; j < 2; ++j) {
    Rr2[j] = 0.f; QXa2[j] = 0.f;
    #pragma unroll
    for (int l = 0; l < 6; ++l) kU6[l][j] = 0.f;
  }

  int pb = 0;
  for (int s = 0; s < S; ++s) {
    float accX[2], accV[2], Pbs[2], Pxcs[2];
    #pragma unroll
    for (int j = 0; j < 2; ++j) { accX[j]=0.f; accV[j]=0.f; Pbs[j]=0.f; Pxcs[j]=0.f; }

    #pragma unroll
    for (int i = 1; i <= 6; ++i) {
      _Float16* bT = base + (pb ? 2304 : 0);
      const float dtA   = dt*(float)TB.A[i];
      const float dt2XF = dt*dt*(float)TB.XF[i];
      const float bi    = (float)TB.b[i];
      const float ci    = (float)TB.cxc[i];
      // phase1: all lanes, 2 cols each (row brow, cols kc0..kc0+1)
      {
        union { _Float16 h[2]; u32 u; } ph, pl;
        #pragma unroll
        for (int j2 = 0; j2 < 2; ++j2) {
          float vv = cvU2[j2] + dtA*fU2[j2];
          float xx = cxU2[j2] + dtA*cvU2[j2] + dt2XF*fU2[j2];
          #pragma unroll
          for (int l = 1; l < i; ++l) {
            vv += (dt*(float)TB.a[i][l]) * kU6[l-1][j2];
            xx += (dt*dt*(float)TB.XC[i][l]) * kU6[l-1][j2];
          }
          float p = vv*xx;
          Pbs[j2] += bi*p; Pxcs[j2] += ci*p;
          _Float16 h, l2; split2s(p, h, l2);
          ph.h[j2] = h; pl.h[j2] = l2;
        }
        *(u32*)(bT + brow*SSTR + kc0)       = ph.u;   // Ph rows 0-7
        *(u32*)(bT + (8+brow)*SSTR + kc0)   = pl.u;   // Pl rows 8-15
      }
      __syncthreads();
      // batched ds_read_b128, then the 8-MFMA chain
      const _Float16* bp = bT + c16*SSTR + q*8;
      v8h B0 = *(const v8h*)(bp);
      v8h B1 = *(const v8h*)(bp + 32);
      v8h B2 = *(const v8h*)(bp + 64);
      v8h B3 = *(const v8h*)(bp + 96);
      v4f C1 = {0,0,0,0}, C2 = {0,0,0,0};
      C1 = MFMAH(Gh[0], B0, C1, 0,0,0);  C2 = MFMAH(Gl[0], B0, C2, 0,0,0);
      C1 = MFMAH(Gh[1], B1, C1, 0,0,0);  C2 = MFMAH(Gl[1], B1, C2, 0,0,0);
      C1 = MFMAH(Gh[2], B2, C1, 0,0,0);  C2 = MFMAH(Gl[2], B2, C2, 0,0,0);
      C1 = MFMAH(Gh[3], B3, C1, 0,0,0);  C2 = MFMAH(Gl[3], B3, C2, 0,0,0);
      // combine; lane^8 exchange via DPP (VALU pipe)
      float kv[4];
      #pragma unroll
      for (int r = 0; r < 4; ++r) {
        float oth = swap8(C1[r]);
        kv[r] = (C1[r] + (oth + C2[r])*INV2048)*INV256;
      }
      float k2 = swap8(kv[2]);
      float k3 = swap8(kv[3]);
      float kva = hiC ? k2 : kv[0];
      float kvb = hiC ? k3 : kv[1];
      kU6[i-1][0] = kva; kU6[i-1][1] = kvb;
      accX[0] += ci*kva; accV[0] += bi*kva;
      accX[1] += ci*kvb; accV[1] += bi*kvb;
      pb ^= 1;
    }

    #pragma unroll
    for (int j = 0; j < 2; ++j) {
      float nx = cxU2[j] + dt*cvU2[j] + dt*dt*(accX[j] + 0.5f*fU2[j]);
      cvU2[j] += dt*(accV[j] + fU2[j]);
      cxU2[j]  = nx;
      QXa2[j] += Rr2[j] + Pxcs[j];
      Rr2[j]  += Pbs[j];
    }
  }

  // ---- epilogue: fill R|QX tiles (rows 0-7 = R, 8-15 = QX; h/l) ----
  __syncthreads();
  _Float16* RQh = base;
  _Float16* RQl = base + 2176;
  {
    union { _Float16 h[2]; u32 u; } t1, t2, t3, t4;
    #pragma unroll
    for (int j2 = 0; j2 < 2; ++j2) {
      _Float16 h, l;
      split2s(Rr2[j2], h, l);  t1.h[j2] = h; t2.h[j2] = l;
      split2s(QXa2[j2], h, l); t3.h[j2] = h; t4.h[j2] = l;
    }
    *(u32*)(RQh + brow*136 + kc0)     = t1.u;
    *(u32*)(RQl + brow*136 + kc0)     = t2.u;
    *(u32*)(RQh + (8+brow)*136 + kc0) = t3.u;
    *(u32*)(RQl + (8+brow)*136 + kc0) = t4.u;
  }
  __syncthreads();

  // LDS staging for coalesced output: ax (8x512 f32), ab (8x512 f32)
  float* axs = (float*)(arena + 9216);
  float* abs_ = (float*)(arena + 25600);

  #pragma unroll
  for (int cbi = 0; cbi < 4; ++cbi) {
    int cb = nb*4 + cbi;
    v4f aH={0,0,0,0}, aC0={0,0,0,0}, aC1={0,0,0,0};
    #pragma unroll
    for (int kb = 0; kb < 4; ++kb) {
      int bo = ((cb*4 + kb)*64 + lane)*8;
      v8h Bh = *(const v8h*)(wH + bo);
      v8h Bl = *(const v8h*)(wL + bo);
      int ao = c16*136 + kb*32 + q*8;
      v8h Ah = *(const v8h*)(RQh + ao);
      v8h Al = *(const v8h*)(RQl + ao);
      aH = MFMAH(Ah, Bh, aH, 0,0,0);
      if (kb & 1) {
        aC1 = MFMAH(Ah, Bl, aC1, 0,0,0);
        aC1 = MFMAH(Al, Bh, aC1, 0,0,0);
      } else {
        aC0 = MFMAH(Ah, Bl, aC0, 0,0,0);
        aC0 = MFMAH(Al, Bh, aC0, 0,0,0);
      }
    }
    float r0 = (aH[0] + (aC0[0]+aC1[0])*INV2048)*INV256;
    float r1 = (aH[1] + (aC0[1]+aC1[1])*INV2048)*INV256;
    float r2 = (aH[2] + (aC0[2]+aC1[2])*INV2048)*INV256;
    float r3 = (aH[3] + (aC0[3]+aC1[3])*INV2048)*INV256;
    float o0 = __shfl_xor(r0, 32, 64);
    float o1 = __shfl_xor(r1, 32, 64);
    float o2 = __shfl_xor(r2, 32, 64);
    float o3 = __shfl_xor(r3, 32, 64);
    if (q < 2) {
      float abv[4] = {r0, r1, r2, r3};
      float axv[4] = {o0, o1, o2, o3};
      #pragma unroll
      for (int i4 = 0; i4 < 4; ++i4) {
        int lrow = 4*q + i4;                 // block-local row 0..7
        int lcol = cb*16 + c16;              // 0..511
        axs[lrow*512 + lcol]  = axv[i4];
        abs_[lrow*512 + lcol] = abv[i4];
      }
    }
  }
  __syncthreads();

  // coalesced drain: each thread handles two float4 chunks per array
  const float Sdt = (float)S * dt;
  #pragma unroll
  for (int half = 0; half < 2; ++half) {
    int flat = half*2048 + tid*4;            // 0..4095, step 4
    int row  = flat >> 9;                    // 0..7
    int col  = flat & 511;
    int go   = (rb + row)*512 + col;
    float4 xv = *(const float4*)(xg + go);
    float4 vv = *(const float4*)(vg + go);
    float4 fv = *(const float4*)(fg + go);
    float4 axf = *(const float4*)(axs + flat);
    float4 abf = *(const float4*)(abs_ + flat);
    float4 o1, o2;
    o1.x = xv.x + Sdt*vv.x + 0.5f*Sdt*Sdt*fv.x - dt*dt*axf.x;
    o1.y = xv.y + Sdt*vv.y + 0.5f*Sdt*Sdt*fv.y - dt*dt*axf.y;
    o1.z = xv.z + Sdt*vv.z + 0.5f*Sdt*Sdt*fv.z - dt*dt*axf.z;
    o1.w = xv.w + Sdt*vv.w + 0.5f*Sdt*Sdt*fv.w - dt*dt*axf.w;
    o2.x = vv.x + Sdt*fv.x - dt*abf.x;
    o2.y = vv.y + Sdt*fv.y - dt*abf.y;
    o2.z = vv.z + Sdt*fv.z - dt*abf.z;
    o2.w = vv.w + Sdt*fv.w - dt*abf.w;
    *(float4*)(outg + go) = o1;
    *(float4*)(outg + 2097152 + go) = o2;
  }
}

extern "C" void kernel_launch(void* const* d_in, const int* in_sizes, int n_in,
                              void* d_out, int out_size, void* d_ws, size_t ws_size,
                              hipStream_t stream) {
  const float* x = (const float*)d_in[0];
  const float* v = (const float*)d_in[1];
  const float* f = (const float*)d_in[2];
  const float* U = (const float*)d_in[3];
  const float* W = (const float*)d_in[4];
  _Float16* ws = (_Float16*)d_ws;

  k_prep<<<dim3(264), dim3(512), 0, stream>>>(U, W, ws);
  dp5_main<<<dim3(512), dim3(512), 0, stream>>>(
      x, v, f, d_in[5], ws, (float*)d_out);
}

// Round 6
// 135.588 us; speedup vs baseline: 1.3048x; 1.0058x over previous
//
#include <hip/hip_runtime.h>

// DP5 integrator, MI355X. fp32 in/out. Rank-128 recursion vs G'=-256·(W@U).
// R19 = R18 + three latency attacks on the 48-stage serial recursion:
//  (1) anti-phase stagger: blocks >=256 sleep ~1200cyc once, so the two
//      co-resident blocks per CU run de-phased (VALU burst of one overlaps
//      DS/MFMA burst of the other; lockstep bursts were the wall).
//  (2) phase1 partial sums for stage i+1 precomputed in stage i's dead
//      window (write->barrier->read latency); only the last tableau term
//      stays on the critical path. Same FMA order -> bit-identical.
//  (3) parallel-DPP combine: one round of independent swap8 + selects
//      replaces the serial swap8->kv->swap8 chain. Identical operand order.
// R18 features kept: fused k_prep, merged projections, coalesced drain.

typedef _Float16 v8h __attribute__((ext_vector_type(8)));
typedef float v4f __attribute__((ext_vector_type(4)));
typedef unsigned short u16;
typedef unsigned int u32;

#define MFMAH __builtin_amdgcn_mfma_f32_16x16x32_f16
#define INV2048 4.8828125e-4f
#define INV256  0.00390625f
#define SSTR 144   // stage tile row stride (halfs)

// lane^8 exchange on the VALU pipe: DPP row_ror:8 (16-lane rows; ror 8 == xor 8)
__device__ __forceinline__ float swap8(float x){
  return __int_as_float(
    __builtin_amdgcn_mov_dpp(__float_as_int(x), 0x128, 0xf, 0xf, true));
}

struct Tab {
  double a[7][7]; double b[7]; double A[7]; double XC[7][7]; double XF[7]; double cxc[7];
};
static constexpr Tab make_tab() {
  Tab t{};
  t.a[2][1]=1.0/5;
  t.a[3][1]=3.0/40;       t.a[3][2]=9.0/40;
  t.a[4][1]=44.0/45;      t.a[4][2]=-56.0/15;      t.a[4][3]=32.0/9;
  t.a[5][1]=19372.0/6561; t.a[5][2]=-25360.0/2187; t.a[5][3]=64448.0/6561; t.a[5][4]=-212.0/729;
  t.a[6][1]=9017.0/3168;  t.a[6][2]=-355.0/33;     t.a[6][3]=46732.0/5247; t.a[6][4]=49.0/176; t.a[6][5]=-5103.0/18656;
  t.b[1]=35.0/384; t.b[2]=0.0; t.b[3]=500.0/1113; t.b[4]=125.0/192; t.b[5]=-2187.0/6784; t.b[6]=11.0/84;
  for (int i=1;i<=6;++i){ double s=0; for(int j=1;j<i;++j) s+=t.a[i][j]; t.A[i]=s; }
  for (int i=1;i<=6;++i) for(int l=1;l<i;++l){ double s=0; for(int j=l+1;j<i;++j) s+=t.a[i][j]*t.a[j][l]; t.XC[i][l]=s; }
  for (int i=1;i<=6;++i){ double s=0; for(int j=1;j<i;++j) s+=t.a[i][j]*t.A[j]; t.XF[i]=s; }
  for (int j=1;j<=6;++j){ double s=0; for (int i=j+1;i<=6;++i) s+=t.b[i]*t.a[i][j]; t.cxc[j]=s; }
  return t;
}
static constexpr Tab TB = make_tab();

__device__ __forceinline__ int decode_steps(const void* p){
  int v = *(const int*)p;
  if (v >= 1 && v <= 512) return v;
  float f = *(const float*)p;
  if (f >= 1.f && f <= 512.f) return (int)f;
  return 8;
}
__device__ __forceinline__ void split2s(float x, _Float16& h, _Float16& l){
  h = (_Float16)x;
  l = (_Float16)((x - (float)h) * 2048.0f);
}

#define WS_GH 0
#define WS_GL 16384
#define WS_UH 32768
#define WS_UL 98304
#define WS_WH 163840
#define WS_WL 229376

// ---- fused prep: blocks 0-7 = G' GEMM from raw U/W; blocks 8-263 = repack ----
__global__ __launch_bounds__(512) void k_prep(const float* __restrict__ Ug,
                                              const float* __restrict__ Wg,
                                              _Float16* __restrict__ ws){
  const int tid = threadIdx.x;
  if (blockIdx.x >= 8) {
    int t = (blockIdx.x - 8)*512 + tid;
    if (t < 65536) {
      int r = t >> 7, c = t & 127;
      _Float16 h, l; split2s(Ug[t]*256.f, h, l);
      int kb=r>>5, q2=(r>>3)&3, j=r&7, n2=c>>4, cl=c&15;
      int slot = ((n2*16+kb)*64 + q2*16+cl)*8 + j;
      ws[WS_UH + slot] = h; ws[WS_UL + slot] = l;
    } else {
      int idx = t - 65536;
      int r = idx >> 9, c = idx & 511;
      _Float16 h, l; split2s(Wg[idx]*256.f, h, l);
      int kb=r>>5, q2=(r>>3)&3, j=r&7, n2=c>>4, cl=c&15;
      int slot = ((n2*4+kb)*64 + q2*16+cl)*8 + j;
      ws[WS_WH + slot] = h; ws[WS_WL + slot] = l;
    }
  } else {
    const int b = blockIdx.x;
    const int ww = tid >> 6, lane = tid & 63, q = lane >> 4, c16 = lane & 15;
    const int nb = ww;
    v4f aH = {0,0,0,0}, aC0 = {0,0,0,0}, aC1 = {0,0,0,0};
    #pragma unroll
    for (int kb = 0; kb < 16; ++kb) {
      const float* wp = Wg + (b*16 + c16)*512 + kb*32 + q*8;
      float4 w0 = *(const float4*)wp;
      float4 w1 = *(const float4*)(wp + 4);
      float wv[8] = {w0.x,w0.y,w0.z,w0.w, w1.x,w1.y,w1.z,w1.w};
      v8h Ah, Al, Bh, Bl;
      #pragma unroll
      for (int j = 0; j < 8; ++j) {
        _Float16 h, l; split2s(-wv[j], h, l);
        Ah[j] = h; Al[j] = l;
        float uv = Ug[(kb*32 + q*8 + j)*128 + nb*16 + c16] * 256.f;
        split2s(uv, h, l);
        Bh[j] = h; Bl[j] = l;
      }
      aH = MFMAH(Ah, Bh, aH, 0,0,0);
      if (kb & 1) {
        aC1 = MFMAH(Ah, Bl, aC1, 0,0,0);
        aC1 = MFMAH(Al, Bh, aC1, 0,0,0);
      } else {
        aC0 = MFMAH(Ah, Bl, aC0, 0,0,0);
        aC0 = MFMAH(Al, Bh, aC0, 0,0,0);
      }
    }
    #pragma unroll
    for (int r = 0; r < 4; ++r) {
      float g = aH[r] + (aC0[r] + aC1[r])*INV2048;
      _Float16 h, l; split2s(g, h, l);
      int m = b*16 + 4*q + r, n = nb*16 + c16;
      int slot = (((n>>4)*4 + (m>>5))*64 + ((m>>3)&3)*16 + (n&15))*8 + (m&7);
      ws[WS_GH + slot] = h; ws[WS_GL + slot] = l;
    }
  }
}

// arena: projections need 2 * 24*520 halfs = 49920 B. Epilogue staging:
// ax at byte 9216 (16KB), ab at 25600 (16KB) -> ends 41984 < 49920.
#define ARENA 49920

__global__ __launch_bounds__(512,4) void dp5_main(
    const float* __restrict__ xg, const float* __restrict__ vg,
    const float* __restrict__ fg, const void* stepsp,
    const _Float16* __restrict__ ws, float* __restrict__ outg)
{
  __shared__ __align__(16) char arena[ARENA];
  _Float16* base = (_Float16*)arena;
  const _Float16* uH = ws + WS_UH;
  const _Float16* uL = ws + WS_UL;
  const _Float16* wH = ws + WS_WH;
  const _Float16* wL = ws + WS_WL;

  // R19: anti-phase stagger — CU pairs are (b, b+256) under round-robin XCD
  // dispatch; delay one of each pair ~1200cyc so co-resident blocks' bursty
  // phases (VALU/DS/MFMA) interleave instead of colliding.
  if (blockIdx.x & 256) __builtin_amdgcn_s_sleep(19);

  const int tid  = threadIdx.x;
  const int ww   = tid >> 6;
  const int lane = tid & 63;
  const int q    = lane >> 4;
  const int c16  = lane & 15;
  const int nb   = ww;
  const int kcol = nb*16 + c16;
  const int srcl = (q>>1)*16 + c16;
  const bool odd = (q & 1);
  const int rb   = blockIdx.x * 8;
  const int S    = decode_steps(stepsp);
  const float dt = 0.01f;
  // row-partner ownership
  const int  brow = c16 & 7;
  const bool hiC  = (c16 >= 8);
  const int  kc0  = nb*16 + 4*q + (hiC ? 2 : 0);   // owns cols kc0, kc0+1

  v8h Gh[4], Gl[4];
  #pragma unroll
  for (int kb = 0; kb < 4; ++kb) {
    int off = ((nb*4 + kb)*64 + lane)*8;
    Gh[kb] = *(const v8h*)(ws + WS_GH + off);
    Gl[kb] = *(const v8h*)(ws + WS_GL + off);
  }

  // ---- merged projections -> xU0/vU0/fU0 in one kb loop ----
  _Float16* tH = base;
  _Float16* tL = base + 12480;
  const int r16 = tid >> 5, c0 = (tid & 31)*16;
  float xU0[2], vU0[2], fU0[2];
  {
    {
      const float* sp = (r16 < 8) ? (xg + (rb + r16)*512) : (vg + (rb + r16 - 8)*512);
      sp += c0;
      float4 g0 = *(const float4*)(sp);
      float4 g1 = *(const float4*)(sp + 4);
      float4 g2 = *(const float4*)(sp + 8);
      float4 g3 = *(const float4*)(sp + 12);
      float vals[16] = {g0.x,g0.y,g0.z,g0.w, g1.x,g1.y,g1.z,g1.w,
                        g2.x,g2.y,g2.z,g2.w, g3.x,g3.y,g3.z,g3.w};
      v8h vh0, vh1, vl0, vl1;
      #pragma unroll
      for (int j = 0; j < 8; ++j) {
        _Float16 h, l;
        split2s(vals[j], h, l);     vh0[j] = h; vl0[j] = l;
        split2s(vals[8+j], h, l);   vh1[j] = h; vl1[j] = l;
      }
      int o = r16*520 + c0;
      *(v8h*)(tH + o) = vh0; *(v8h*)(tH + o + 8) = vh1;
      *(v8h*)(tL + o) = vl0; *(v8h*)(tL + o + 8) = vl1;
    }
    if (r16 < 8) {
      const float* sp = fg + (rb + r16)*512 + c0;
      float4 g0 = *(const float4*)(sp);
      float4 g1 = *(const float4*)(sp + 4);
      float4 g2 = *(const float4*)(sp + 8);
      float4 g3 = *(const float4*)(sp + 12);
      float vals[16] = {g0.x,g0.y,g0.z,g0.w, g1.x,g1.y,g1.z,g1.w,
                        g2.x,g2.y,g2.z,g2.w, g3.x,g3.y,g3.z,g3.w};
      v8h vh0, vh1, vl0, vl1;
      #pragma unroll
      for (int j = 0; j < 8; ++j) {
        _Float16 h, l;
        split2s(vals[j], h, l);     vh0[j] = h; vl0[j] = l;
        split2s(vals[8+j], h, l);   vh1[j] = h; vl1[j] = l;
      }
      int o = (16 + r16)*520 + c0;
      *(v8h*)(tH + o) = vh0; *(v8h*)(tH + o + 8) = vh1;
      *(v8h*)(tL + o) = vl0; *(v8h*)(tL + o + 8) = vl1;
    }
    __syncthreads();

    v4f aH0={0,0,0,0}, aH1={0,0,0,0}, aC0={0,0,0,0}, aC1={0,0,0,0};
    v4f bH0={0,0,0,0}, bH1={0,0,0,0}, bC0={0,0,0,0}, bC1={0,0,0,0};
    const int arow1 = (c16 < 8) ? (16 + c16) : c16;
    #pragma unroll
    for (int kb = 0; kb < 16; ++kb) {
      int ao0 = c16*520 + kb*32 + q*8;
      int ao1 = arow1*520 + kb*32 + q*8;
      v8h Ah0 = *(const v8h*)(tH + ao0);
      v8h Al0 = *(const v8h*)(tL + ao0);
      v8h Ah1 = *(const v8h*)(tH + ao1);
      v8h Al1 = *(const v8h*)(tL + ao1);
      int bo = ((nb*16 + kb)*64 + lane)*8;
      v8h Bh = *(const v8h*)(uH + bo);
      v8h Bl = *(const v8h*)(uL + bo);
      if (kb & 1) {
        aH1 = MFMAH(Ah0, Bh, aH1, 0,0,0);
        aC1 = MFMAH(Ah0, Bl, aC1, 0,0,0);
        aC1 = MFMAH(Al0, Bh, aC1, 0,0,0);
        bH1 = MFMAH(Ah1, Bh, bH1, 0,0,0);
        bC1 = MFMAH(Ah1, Bl, bC1, 0,0,0);
        bC1 = MFMAH(Al1, Bh, bC1, 0,0,0);
      } else {
        aH0 = MFMAH(Ah0, Bh, aH0, 0,0,0);
        aC0 = MFMAH(Ah0, Bl, aC0, 0,0,0);
        aC0 = MFMAH(Al0, Bh, aC0, 0,0,0);
        bH0 = MFMAH(Ah1, Bh, bH0, 0,0,0);
        bC0 = MFMAH(Ah1, Bl, bC0, 0,0,0);
        bC0 = MFMAH(Al1, Bh, bC0, 0,0,0);
      }
    }
    float at0 = ((aH0[0]+aH1[0]) + (aC0[0]+aC1[0])*INV2048)*INV256;
    float at1 = ((aH0[1]+aH1[1]) + (aC0[1]+aC1[1])*INV2048)*INV256;
    float at2 = ((aH0[2]+aH1[2]) + (aC0[2]+aC1[2])*INV2048)*INV256;
    float at3 = ((aH0[3]+aH1[3]) + (aC0[3]+aC1[3])*INV2048)*INV256;
    float bt0 = ((bH0[0]+bH1[0]) + (bC0[0]+bC1[0])*INV2048)*INV256;
    float bt1 = ((bH0[1]+bH1[1]) + (bC0[1]+bC1[1])*INV2048)*INV256;
    float bt2 = ((bH0[2]+bH1[2]) + (bC0[2]+bC1[2])*INV2048)*INV256;
    float bt3 = ((bH0[3]+bH1[3]) + (bC0[3]+bC1[3])*INV2048)*INV256;
    {
      float sx0=__shfl(at0,srcl,64), sx1=__shfl(at1,srcl,64);
      float sx2=__shfl(at2,srcl,64), sx3=__shfl(at3,srcl,64);
      xU0[0] = odd ? sx2 : sx0; xU0[1] = odd ? sx3 : sx1;
      int srclv = srcl + 32;
      float sv0=__shfl(at0,srclv,64), sv1=__shfl(at1,srclv,64);
      float sv2=__shfl(at2,srclv,64), sv3=__shfl(at3,srclv,64);
      vU0[0] = odd ? sv2 : sv0; vU0[1] = odd ? sv3 : sv1;
    }
    {
      float sf0=__shfl(bt0,srcl,64), sf1=__shfl(bt1,srcl,64);
      float sf2=__shfl(bt2,srcl,64), sf3=__shfl(bt3,srcl,64);
      fU0[0] = odd ? sf2 : sf0; fU0[1] = odd ? sf3 : sf1;
    }
    __syncthreads();
  }

  // ---- bounce spread -> row-partner state (float2 per lane) ----
  float cxU2[2], cvU2[2], fU2[2];
  {
    float* T = (float*)arena;
    #pragma unroll
    for (int p2 = 0; p2 < 3; ++p2) {
      float i0 = (p2==0) ? xU0[0] : (p2==1) ? vU0[0] : fU0[0];
      float i1 = (p2==0) ? xU0[1] : (p2==1) ? vU0[1] : fU0[1];
      T[(2*q + 0)*132 + kcol] = i0;
      T[(2*q + 1)*132 + kcol] = i1;
      __syncthreads();
      float2 t2 = *(const float2*)(T + brow*132 + kc0);
      float* o = (p2==0) ? cxU2 : (p2==1) ? cvU2 : fU2;
      o[0] = t2.x; o[1] = t2.y;
      __syncthreads();
    }
  }

  // ---- rank-128 recursion: transposed GEMM, balanced phase1 ----
  float kU6[6][2], Rr2[2], QXa2[2];
  #pragma unroll
  for (int j = 0; j < 2; ++j) {
    Rr2[j] = 0.f; QXa2[j] = 0.f;
    #pragma unroll
    for (int l = 0; l < 6; ++l) kU6[l][j] = 0.f;
  }

  int pb = 0;
  for (int s = 0; s < S; ++s) {
    float accX[2], accV[2], Pbs[2], Pxcs[2];
    #pragma unroll
    for (int j = 0; j < 2; ++j) { accX[j]=0.f; accV[j]=0.f; Pbs[j]=0.f; Pxcs[j]=0.f; }

    // R19: running partial sums for phase1 (all but the last tableau term).
    float vvP[2], xxP[2];
    #pragma unroll
    for (int j2 = 0; j2 < 2; ++j2) {
      vvP[j2] = cvU2[j2] + (dt*(float)TB.A[1])*fU2[j2];
      xxP[j2] = cxU2[j2] + (dt*(float)TB.A[1])*cvU2[j2] + (dt*dt*(float)TB.XF[1])*fU2[j2];
    }

    #pragma unroll
    for (int i = 1; i <= 6; ++i) {
      _Float16* bT = base + (pb ? 2304 : 0);
      const float bi    = (float)TB.b[i];
      const float ci    = (float)TB.cxc[i];
      // phase1: partials + (last term only, for i>=2)
      {
        union { _Float16 h[2]; u32 u; } ph, pl;
        #pragma unroll
        for (int j2 = 0; j2 < 2; ++j2) {
          float vv = vvP[j2];
          float xx = xxP[j2];
          if (i >= 2) {
            vv += (dt*(float)TB.a[i][i-1]) * kU6[i-2][j2];
            xx += (dt*dt*(float)TB.XC[i][i-1]) * kU6[i-2][j2];
          }
          float p = vv*xx;
          Pbs[j2] += bi*p; Pxcs[j2] += ci*p;
          _Float16 h, l2; split2s(p, h, l2);
          ph.h[j2] = h; pl.h[j2] = l2;
        }
        *(u32*)(bT + brow*SSTR + kc0)       = ph.u;   // Ph rows 0-7
        *(u32*)(bT + (8+brow)*SSTR + kc0)   = pl.u;   // Pl rows 8-15
      }
      // R19: precompute stage-(i+1) partials in the dead window before the
      // barrier (uses only kU6[0..i-2], all available). Same add order.
      if (i < 6) {
        #pragma unroll
        for (int j2 = 0; j2 < 2; ++j2) {
          float vv = cvU2[j2] + (dt*(float)TB.A[i+1])*fU2[j2];
          float xx = cxU2[j2] + (dt*(float)TB.A[i+1])*cvU2[j2] + (dt*dt*(float)TB.XF[i+1])*fU2[j2];
          #pragma unroll
          for (int l = 1; l < i; ++l) {
            vv += (dt*(float)TB.a[i+1][l]) * kU6[l-1][j2];
            xx += (dt*dt*(float)TB.XC[i+1][l]) * kU6[l-1][j2];
          }
          vvP[j2] = vv; xxP[j2] = xx;
        }
      }
      __syncthreads();
      // batched ds_read_b128, then the 8-MFMA chain
      const _Float16* bp = bT + c16*SSTR + q*8;
      v8h B0 = *(const v8h*)(bp);
      v8h B1 = *(const v8h*)(bp + 32);
      v8h B2 = *(const v8h*)(bp + 64);
      v8h B3 = *(const v8h*)(bp + 96);
      v4f C1 = {0,0,0,0}, C2 = {0,0,0,0};
      C1 = MFMAH(Gh[0], B0, C1, 0,0,0);  C2 = MFMAH(Gl[0], B0, C2, 0,0,0);
      C1 = MFMAH(Gh[1], B1, C1, 0,0,0);  C2 = MFMAH(Gl[1], B1, C2, 0,0,0);
      C1 = MFMAH(Gh[2], B2, C1, 0,0,0);  C2 = MFMAH(Gl[2], B2, C2, 0,0,0);
      C1 = MFMAH(Gh[3], B3, C1, 0,0,0);  C2 = MFMAH(Gl[3], B3, C2, 0,0,0);
      // R19: parallel-DPP combine (one independent swap8 round + selects).
      // lo (c16<8):  kva = (C1[0] + (swap8(C1[0]) + C2[0])*I2048)*I256
      // hi (c16>=8): kva = (swap8(C1[2]) + (C1[2] + swap8(C2[2]))*I2048)*I256
      {
        float sa0 = swap8(C1[0]), sa2 = swap8(C1[2]), sc2 = swap8(C2[2]);
        float sb1 = swap8(C1[1]), sb3 = swap8(C1[3]), sd3 = swap8(C2[3]);
        float m_a = hiC ? sa2   : C1[0];
        float n_a = hiC ? C1[2] : sa0;
        float c_a = hiC ? sc2   : C2[0];
        float m_b = hiC ? sb3   : C1[1];
        float n_b = hiC ? C1[3] : sb1;
        float c_b = hiC ? sd3   : C2[1];
        float kva = (m_a + (n_a + c_a)*INV2048)*INV256;
        float kvb = (m_b + (n_b + c_b)*INV2048)*INV256;
        kU6[i-1][0] = kva; kU6[i-1][1] = kvb;
        accX[0] += ci*kva; accV[0] += bi*kva;
        accX[1] += ci*kvb; accV[1] += bi*kvb;
      }
      pb ^= 1;
    }

    #pragma unroll
    for (int j = 0; j < 2; ++j) {
      float nx = cxU2[j] + dt*cvU2[j] + dt*dt*(accX[j] + 0.5f*fU2[j]);
      cvU2[j] += dt*(accV[j] + fU2[j]);
      cxU2[j]  = nx;
      QXa2[j] += Rr2[j] + Pxcs[j];
      Rr2[j]  += Pbs[j];
    }
  }

  // ---- epilogue: fill R|QX tiles (rows 0-7 = R, 8-15 = QX; h/l) ----
  __syncthreads();
  _Float16* RQh = base;
  _Float16* RQl = base + 2176;
  {
    union { _Float16 h[2]; u32 u; } t1, t2, t3, t4;
    #pragma unroll
    for (int j2 = 0; j2 < 2; ++j2) {
      _Float16 h, l;
      split2s(Rr2[j2], h, l);  t1.h[j2] = h; t2.h[j2] = l;
      split2s(QXa2[j2], h, l); t3.h[j2] = h; t4.h[j2] = l;
    }
    *(u32*)(RQh + brow*136 + kc0)     = t1.u;
    *(u32*)(RQl + brow*136 + kc0)     = t2.u;
    *(u32*)(RQh + (8+brow)*136 + kc0) = t3.u;
    *(u32*)(RQl + (8+brow)*136 + kc0) = t4.u;
  }
  __syncthreads();

  // LDS staging for coalesced output: ax (8x512 f32), ab (8x512 f32)
  float* axs = (float*)(arena + 9216);
  float* abs_ = (float*)(arena + 25600);

  #pragma unroll
  for (int cbi = 0; cbi < 4; ++cbi) {
    int cb = nb*4 + cbi;
    v4f aH={0,0,0,0}, aC0={0,0,0,0}, aC1={0,0,0,0};
    #pragma unroll
    for (int kb = 0; kb < 4; ++kb) {
      int bo = ((cb*4 + kb)*64 + lane)*8;
      v8h Bh = *(const v8h*)(wH + bo);
      v8h Bl = *(const v8h*)(wL + bo);
      int ao = c16*136 + kb*32 + q*8;
      v8h Ah = *(const v8h*)(RQh + ao);
      v8h Al = *(const v8h*)(RQl + ao);
      aH = MFMAH(Ah, Bh, aH, 0,0,0);
      if (kb & 1) {
        aC1 = MFMAH(Ah, Bl, aC1, 0,0,0);
        aC1 = MFMAH(Al, Bh, aC1, 0,0,0);
      } else {
        aC0 = MFMAH(Ah, Bl, aC0, 0,0,0);
        aC0 = MFMAH(Al, Bh, aC0, 0,0,0);
      }
    }
    float r0 = (aH[0] + (aC0[0]+aC1[0])*INV2048)*INV256;
    float r1 = (aH[1] + (aC0[1]+aC1[1])*INV2048)*INV256;
    float r2 = (aH[2] + (aC0[2]+aC1[2])*INV2048)*INV256;
    float r3 = (aH[3] + (aC0[3]+aC1[3])*INV2048)*INV256;
    float o0 = __shfl_xor(r0, 32, 64);
    float o1 = __shfl_xor(r1, 32, 64);
    float o2 = __shfl_xor(r2, 32, 64);
    float o3 = __shfl_xor(r3, 32, 64);
    if (q < 2) {
      float abv[4] = {r0, r1, r2, r3};
      float axv[4] = {o0, o1, o2, o3};
      #pragma unroll
      for (int i4 = 0; i4 < 4; ++i4) {
        int lrow = 4*q + i4;                 // block-local row 0..7
        int lcol = cb*16 + c16;              // 0..511
        axs[lrow*512 + lcol]  = axv[i4];
        abs_[lrow*512 + lcol] = abv[i4];
      }
    }
  }
  __syncthreads();

  // coalesced drain: each thread handles two float4 chunks per array
  const float Sdt = (float)S * dt;
  #pragma unroll
  for (int half = 0; half < 2; ++half) {
    int flat = half*2048 + tid*4;            // 0..4095, step 4
    int row  = flat >> 9;                    // 0..7
    int col  = flat & 511;
    int go   = (rb + row)*512 + col;
    float4 xv = *(const float4*)(xg + go);
    float4 vv = *(const float4*)(vg + go);
    float4 fv = *(const float4*)(fg + go);
    float4 axf = *(const float4*)(axs + flat);
    float4 abf = *(const float4*)(abs_ + flat);
    float4 o1, o2;
    o1.x = xv.x + Sdt*vv.x + 0.5f*Sdt*Sdt*fv.x - dt*dt*axf.x;
    o1.y = xv.y + Sdt*vv.y + 0.5f*Sdt*Sdt*fv.y - dt*dt*axf.y;
    o1.z = xv.z + Sdt*vv.z + 0.5f*Sdt*Sdt*fv.z - dt*dt*axf.z;
    o1.w = xv.w + Sdt*vv.w + 0.5f*Sdt*Sdt*fv.w - dt*dt*axf.w;
    o2.x = vv.x + Sdt*fv.x - dt*abf.x;
    o2.y = vv.y + Sdt*fv.y - dt*abf.y;
    o2.z = vv.z + Sdt*fv.z - dt*abf.z;
    o2.w = vv.w + Sdt*fv.w - dt*abf.w;
    *(float4*)(outg + go) = o1;
    *(float4*)(outg + 2097152 + go) = o2;
  }
}

extern "C" void kernel_launch(void* const* d_in, const int* in_sizes, int n_in,
                              void* d_out, int out_size, void* d_ws, size_t ws_size,
                              hipStream_t stream) {
  const float* x = (const float*)d_in[0];
  const float* v = (const float*)d_in[1];
  const float* f = (const float*)d_in[2];
  const float* U = (const float*)d_in[3];
  const float* W = (const float*)d_in[4];
  _Float16* ws = (_Float16*)d_ws;

  k_prep<<<dim3(264), dim3(512), 0, stream>>>(U, W, ws);
  dp5_main<<<dim3(512), dim3(512), 0, stream>>>(
      x, v, f, d_in[5], ws, (float*)d_out);
}